// Round 2
// baseline (101.602 us; speedup 1.0000x reference)
//
#include <hip/hip_runtime.h>
#include <hip/hip_bf16.h>

typedef unsigned short u16;
typedef __attribute__((ext_vector_type(8))) short short8;
typedef __attribute__((ext_vector_type(4))) float floatx4;

#define NROWS 8192
#define DIM 256

__device__ __forceinline__ void atomicMinFloat(float* addr, float val) {
    if (val >= 0.0f) {
        atomicMin((int*)addr, __float_as_int(val));
    } else {
        atomicMax((unsigned int*)addr, __float_as_uint(val));
    }
}

__device__ __forceinline__ u16 f32_to_bf16_rne(float x) {
    unsigned int u = __float_as_uint(x);
    unsigned int r = (u + 0x7fffu + ((u >> 16) & 1u)) >> 16;
    return (u16)r;
}

// C(M) = -logp * exp(logp); quasiconcave in M => rowmin = min(C(minM), C(maxM)).
__device__ __forceinline__ float c_of_m(float m) {
    const float INV_SIG = 1.0f / 0.3f;
    const float KC = 0.28503427f;  // -ln(0.3) - 0.5*ln(2*pi)
    float z = (m - 1.0f) * INV_SIG;
    float logp = fmaf(-0.5f * z, z, KC);
    return -logp * __expf(logp);
}

// Normalize rows (L2-norm clamped at 1e-8), wave per row, float4 loads.
// BOTH X and Y are written in MFMA fragment ("panel") layout:
//   element (row r, k) -> flat[ ((p*8+kt)*64 + lq*16 + lm)*8 + j ]
//   p=r>>4, lm=r&15, kt=k>>5, lq=(k>>3)&3, j=k&7.
// A fragment load is then base + lane*16B: one coalesced dwordx4.
// Verified end-to-end R5/R11/R14/R15 (absmax 1.5e-5).
__global__ __launch_bounds__(256) void normalize_kernel(const float* __restrict__ Ex,
                                                        const float* __restrict__ Ey,
                                                        u16* __restrict__ Xs,
                                                        u16* __restrict__ Ys,
                                                        float* __restrict__ out) {
    const int t = threadIdx.x;
    const int ln = t & 63;
    const int row = blockIdx.x * 4 + (t >> 6);
    const float* src = (blockIdx.y == 0) ? Ex : Ey;
    u16* dst = (blockIdx.y == 0) ? Xs : Ys;

    float4 v = *(const float4*)(src + (size_t)row * DIM + ln * 4);
    float s = fmaf(v.x, v.x, fmaf(v.y, v.y, fmaf(v.z, v.z, v.w * v.w)));
    #pragma unroll
    for (int m = 32; m >= 1; m >>= 1) s += __shfl_xor(s, m, 64);
    float inv = 1.0f / fmaxf(sqrtf(s), 1e-8f);

    ushort4 o;
    o.x = f32_to_bf16_rne(v.x * inv);
    o.y = f32_to_bf16_rne(v.y * inv);
    o.z = f32_to_bf16_rne(v.z * inv);
    o.w = f32_to_bf16_rne(v.w * inv);

    const int p = row >> 4;
    const int lm = row & 15;
    const int kt = ln >> 3;
    const int lq = (ln >> 1) & 3;
    const int j4 = (ln & 1) * 4;
    const size_t off = ((size_t)((p * 8 + kt) * 64 + lq * 16 + lm)) * 8 + j4;
    *(ushort4*)(dst + off) = o;

    if (blockIdx.y == 0 && ln == 0) out[row] = __uint_as_float(0x7f800000u);  // +inf
}

// R18: NO LDS, NO __syncthreads. Block = 512 rows x 512 cols, 8 waves, each
// wave a distinct 64-row group (A resident in 128 VGPRs); B fragments are
// read DIRECTLY from the L2/L1-resident panel-layout Ys (same addresses the
// DMA staging used; 1 KB coalesced dwordx4 per fragment). Rationale (R17
// post-mortem): the per-ct __syncthreads drained vmcnt(0) and re-locksteped
// both waves/SIMD, serializing the LDS phase (3.1k cyc/ct) with the MFMA
// phase (5.0k cyc/ct). Without barriers the compiler emits the counted-vmcnt
// MFMA<->load interleave; all 8 waves read identical B addresses so L1
// (32 KB = one ct tile) serves 7/8 reads. A raw s_barrier per ct (no memory
// semantics -- loads stay in flight) bounds wave skew to keep L1 reuse.
// XCD swizzle: each XCD owns 4 row-tiles x 8 col-groups => A 1 MB + B 2 MB
// = 3 MB < 4 MB per-XCD L2.
__global__ void __launch_bounds__(512, 2)
gemm_min_kernel(const u16* __restrict__ Xs,
                const u16* __restrict__ Ys,
                float* __restrict__ out) {
    const int tid = threadIdx.x;
    const int w = tid >> 6;      // 0..7 row-group
    const int lane = tid & 63;
    const int lq = lane >> 4;
    const int lm = lane & 15;

    // XCD-aware remap (dispatch i -> XCD i&7 round-robin): XCD x gets a
    // 4 row-tile x 8 col-group region. Bijective over the 16x16 grid.
    const int i = blockIdx.x;
    const int x = i & 7;
    const int jj = i >> 3;                  // 0..31 within XCD
    const int rt = (x & 3) * 4 + (jj & 3);  // row-tile 0..15
    const int cgrp = (x >> 2) * 8 + (jj >> 2);  // col-group 0..15

    const int rowStart = rt * 512;
    const int rowPan0 = rt * 32 + w * 4;
    const u16* ybase = Ys + (size_t)cgrp * 32 * 4096;  // advances 16384/ct

    short8 a[4][8];
    auto loadA = [&](int kt) {
        #pragma unroll
        for (int rg = 0; rg < 4; ++rg)
            a[rg][kt] = *(const short8*)(
                Xs + ((size_t)(rowPan0 + rg) * 8 + kt) * 512 + lane * 8);
    };
    loadA(0); loadA(1); loadA(2); loadA(3);
    loadA(4); loadA(5); loadA(6); loadA(7);

    floatx4 mn4[4], mx4[4];
    #pragma unroll
    for (int rg = 0; rg < 4; ++rg) {
        mn4[rg] = (floatx4){3.4e38f, 3.4e38f, 3.4e38f, 3.4e38f};
        mx4[rg] = (floatx4){-3.4e38f, -3.4e38f, -3.4e38f, -3.4e38f};
    }

    floatx4 acc[4][4];
    const floatx4 FZ = (floatx4){0.0f, 0.0f, 0.0f, 0.0f};

    #pragma unroll 1
    for (int ct = 0; ct < 8; ++ct) {
        if (ct) __builtin_amdgcn_s_barrier();  // timing-only: bound wave skew for L1 reuse
        #pragma unroll
        for (int kt = 0; kt < 8; ++kt) {
            short8 bf[4];
            #pragma unroll
            for (int cg = 0; cg < 4; ++cg)
                bf[cg] = *(const short8*)(ybase + cg * 4096 + kt * 512 + lane * 8);
            __builtin_amdgcn_s_setprio(1);
            if (kt == 0) {
                #pragma unroll
                for (int cg = 0; cg < 4; ++cg)
                    #pragma unroll
                    for (int rg = 0; rg < 4; ++rg)
                        acc[rg][cg] = __builtin_amdgcn_mfma_f32_16x16x32_bf16(
                            a[rg][0], bf[cg], FZ, 0, 0, 0);
            } else {
                #pragma unroll
                for (int cg = 0; cg < 4; ++cg)
                    #pragma unroll
                    for (int rg = 0; rg < 4; ++rg)
                        acc[rg][cg] = __builtin_amdgcn_mfma_f32_16x16x32_bf16(
                            a[rg][kt], bf[cg], acc[rg][cg], 0, 0, 0);
            }
            __builtin_amdgcn_s_setprio(0);
        }
        // fold: per-ct min/max of M into running trackers
        #pragma unroll
        for (int rg = 0; rg < 4; ++rg)
            #pragma unroll
            for (int cg = 0; cg < 4; ++cg)
                #pragma unroll
                for (int r = 0; r < 4; ++r) {
                    float m = acc[rg][cg][r];
                    mn4[rg][r] = fminf(mn4[rg][r], m);
                    mx4[rg][r] = fmaxf(mx4[rg][r], m);
                }
        ybase += 16384;  // loop-carried: blocks cross-ct hoisting
    }

    // Single epilogue: quad-lane reduce, eval C twice (quasiconcavity),
    // fire-and-forget atomicMin (no read guard -- R3 post-mortem).
    #pragma unroll
    for (int rg = 0; rg < 4; ++rg) {
        #pragma unroll
        for (int r = 0; r < 4; ++r) {
            float mn = mn4[rg][r];
            float mx = mx4[rg][r];
            #pragma unroll
            for (int mofs = 1; mofs < 16; mofs <<= 1) {
                mn = fminf(mn, __shfl_xor(mn, mofs, 64));
                mx = fmaxf(mx, __shfl_xor(mx, mofs, 64));
            }
            if (lm == 0) {
                float cmin = fminf(c_of_m(mn), c_of_m(mx));
                int row = rowStart + w * 64 + rg * 16 + lq * 4 + r;
                atomicMinFloat(&out[row], cmin);
            }
        }
    }
}

extern "C" void kernel_launch(void* const* d_in, const int* in_sizes, int n_in,
                              void* d_out, int out_size, void* d_ws, size_t ws_size,
                              hipStream_t stream) {
    const float* Ex = (const float*)d_in[0];
    const float* Ey = (const float*)d_in[1];
    float* out = (float*)d_out;
    u16* Xs = (u16*)d_ws;                // 4 MB, panel layout
    u16* Ys = Xs + (size_t)NROWS * DIM;  // 4 MB, panel layout

    hipLaunchKernelGGL(normalize_kernel, dim3(NROWS / 4, 2), dim3(256), 0, stream,
                       Ex, Ey, Xs, Ys, out);
    hipLaunchKernelGGL(gemm_min_kernel, dim3(16 * 16), dim3(512), 0, stream,
                       Xs, Ys, out);
}

// Round 3
// 96.626 us; speedup vs baseline: 1.0515x; 1.0515x over previous
//
#include <hip/hip_runtime.h>
#include <hip/hip_bf16.h>

typedef unsigned short u16;
typedef __attribute__((ext_vector_type(8))) short short8;
typedef __attribute__((ext_vector_type(4))) float floatx4;

#define NROWS 8192
#define DIM 256

__device__ __forceinline__ void atomicMinFloat(float* addr, float val) {
    if (val >= 0.0f) {
        atomicMin((int*)addr, __float_as_int(val));
    } else {
        atomicMax((unsigned int*)addr, __float_as_uint(val));
    }
}

__device__ __forceinline__ u16 f32_to_bf16_rne(float x) {
    unsigned int u = __float_as_uint(x);
    unsigned int r = (u + 0x7fffu + ((u >> 16) & 1u)) >> 16;
    return (u16)r;
}

// C(M) = -logp * exp(logp); quasiconcave in M => rowmin = min(C(minM), C(maxM)).
__device__ __forceinline__ float c_of_m(float m) {
    const float INV_SIG = 1.0f / 0.3f;
    const float KC = 0.28503427f;  // -ln(0.3) - 0.5*ln(2*pi)
    float z = (m - 1.0f) * INV_SIG;
    float logp = fmaf(-0.5f * z, z, KC);
    return -logp * __expf(logp);
}

// 16B async DMA global -> LDS. LDS dest is wave-uniform base + lane*16.
__device__ __forceinline__ void load16(const u16* g, u16* l) {
    __builtin_amdgcn_global_load_lds(
        (__attribute__((address_space(1))) void*)g,
        (__attribute__((address_space(3))) void*)l, 16, 0, 0);
}

// Normalize rows (L2-norm clamped at 1e-8), wave per row, float4 loads.
// BOTH X and Y are written in MFMA fragment ("panel") layout:
//   element (row r, k) -> flat[ ((p*8+kt)*64 + lq*16 + lm)*8 + j ]
//   p=r>>4, lm=r&15, kt=k>>5, lq=(k>>3)&3, j=k&7.
// A fragment load is then base + lane*16B: one coalesced dwordx4.
// Verified end-to-end R5/R11/R14/R15 (absmax 1.5e-5).
__global__ __launch_bounds__(256) void normalize_kernel(const float* __restrict__ Ex,
                                                        const float* __restrict__ Ey,
                                                        u16* __restrict__ Xs,
                                                        u16* __restrict__ Ys,
                                                        float* __restrict__ out) {
    const int t = threadIdx.x;
    const int ln = t & 63;
    const int row = blockIdx.x * 4 + (t >> 6);
    const float* src = (blockIdx.y == 0) ? Ex : Ey;
    u16* dst = (blockIdx.y == 0) ? Xs : Ys;

    float4 v = *(const float4*)(src + (size_t)row * DIM + ln * 4);
    float s = fmaf(v.x, v.x, fmaf(v.y, v.y, fmaf(v.z, v.z, v.w * v.w)));
    #pragma unroll
    for (int m = 32; m >= 1; m >>= 1) s += __shfl_xor(s, m, 64);
    float inv = 1.0f / fmaxf(sqrtf(s), 1e-8f);

    ushort4 o;
    o.x = f32_to_bf16_rne(v.x * inv);
    o.y = f32_to_bf16_rne(v.y * inv);
    o.z = f32_to_bf16_rne(v.z * inv);
    o.w = f32_to_bf16_rne(v.w * inv);

    const int p = row >> 4;
    const int lm = row & 15;
    const int kt = ln >> 3;
    const int lq = (ln >> 1) & 3;
    const int j4 = (ln & 1) * 4;
    const size_t off = ((size_t)((p * 8 + kt) * 64 + lq * 16 + lm)) * 8 + j4;
    *(ushort4*)(dst + off) = o;

    if (blockIdx.y == 0 && ln == 0) out[row] = __uint_as_float(0x7f800000u);  // +inf
}

// R19: LDS double-buffer restored (R18's direct-global B spilled: VGPR=128,
// 2 MB scratch writes) + the proven 8-phase T3/T4/T5 schedule applied to the
// kt loop. Block = 512 rows x 512 cols, 8 waves, wave w owns 64 rows (A
// resident: a[4][8] = 128 VGPR); all waves share each 64-col B tile in LDS.
// Per col-tile (ct), 8 phases (one per kt): {4x ds_read_b128 B-frags ||
// 1 staging DMA for buf^1 (phases 0-3) -> s_barrier -> setprio(1) 16 MFMA
// setprio(0) -> s_barrier}. MFMA clusters stay aligned across waves while
// the next phase's LDS reads + next ct's DMA issue underneath (T3); the only
// vmcnt drain is one __syncthreads per ct whose DMAs were issued >=4 phases
// (~3k cyc) earlier -- a free drain (T4). setprio now has per-phase role
// diversity to arbitrate (T5's confirmed regime).
// XCD swizzle: each XCD owns 4 row-tiles x 8 col-groups => A 1 MB + B 2 MB
// = 3 MB < 4 MB per-XCD L2.
__global__ void __launch_bounds__(512, 2)
gemm_min_kernel(const u16* __restrict__ Xs,
                const u16* __restrict__ Ys,
                float* __restrict__ out) {
    __shared__ u16 Bs[2][32 * 512];  // 2 x 32 KB

    const int tid = threadIdx.x;
    const int w = tid >> 6;      // 0..7 row-group
    const int lane = tid & 63;
    const int lq = lane >> 4;
    const int lm = lane & 15;

    // XCD-aware remap (dispatch i -> XCD i&7 round-robin): XCD x gets a
    // 4 row-tile x 8 col-group region. Bijective over the 16x16 grid.
    const int i = blockIdx.x;
    const int x = i & 7;
    const int jj = i >> 3;                      // 0..31 within XCD
    const int rt = (x & 3) * 4 + (jj & 3);      // row-tile 0..15
    const int cgrp = (x >> 2) * 8 + (jj >> 2);  // col-group 0..15

    const int rowStart = rt * 512;
    const int rowPan0 = rt * 32 + w * 4;
    const u16* ybase = Ys + (size_t)cgrp * 32 * 4096;  // advances 16384/ct

    // Stage one 64col x 256k B tile (32 KB = 32 x 1 KB units) via DMA.
    // 8 waves x 4 units; unit u -> (panel u>>3, kt u&7); LDS slot u*512 so
    // fragment reads are Bs[(cg*8+kt)*512 + lane*8] (b128, conflict-free).
    auto stage1 = [&](int buf, const u16* yb, int iu) {
        const int u = w * 4 + iu;
        load16(yb + (u >> 3) * 4096 + (u & 7) * 512 + lane * 8,
               &Bs[buf][u * 512]);
    };

    short8 a[4][8];
    auto loadA = [&](int kt) {
        #pragma unroll
        for (int rg = 0; rg < 4; ++rg)
            a[rg][kt] = *(const short8*)(
                Xs + ((size_t)(rowPan0 + rg) * 8 + kt) * 512 + lane * 8);
    };

    floatx4 mn4[4], mx4[4];
    #pragma unroll
    for (int rg = 0; rg < 4; ++rg) {
        mn4[rg] = (floatx4){3.4e38f, 3.4e38f, 3.4e38f, 3.4e38f};
        mx4[rg] = (floatx4){-3.4e38f, -3.4e38f, -3.4e38f, -3.4e38f};
    }

    floatx4 acc[4][4];
    const floatx4 FZ = (floatx4){0.0f, 0.0f, 0.0f, 0.0f};

    // --- prologue: stage buf0 fully, load A, drain ---
    stage1(0, ybase, 0); stage1(0, ybase, 1);
    stage1(0, ybase, 2); stage1(0, ybase, 3);
    loadA(0); loadA(1); loadA(2); loadA(3);
    loadA(4); loadA(5); loadA(6); loadA(7);
    __syncthreads();

    #pragma unroll 1
    for (int ct = 0; ct < 8; ++ct) {
        const int buf = ct & 1;
        if (ct) __syncthreads();  // drains buf's DMA (issued >=4 phases ago)
        const u16* bsb = &Bs[buf][0];
        const u16* ynext = ybase + 16384;

        #pragma unroll
        for (int kt = 0; kt < 8; ++kt) {
            short8 bf[4];
            #pragma unroll
            for (int cg = 0; cg < 4; ++cg)
                bf[cg] = *(const short8*)(bsb + (cg * 8 + kt) * 512 + lane * 8);
            if (kt < 4 && ct < 7) stage1(buf ^ 1, ynext, kt);
            __builtin_amdgcn_s_barrier();
            __builtin_amdgcn_s_setprio(1);
            if (kt == 0) {
                #pragma unroll
                for (int cg = 0; cg < 4; ++cg)
                    #pragma unroll
                    for (int rg = 0; rg < 4; ++rg)
                        acc[rg][cg] = __builtin_amdgcn_mfma_f32_16x16x32_bf16(
                            a[rg][0], bf[cg], FZ, 0, 0, 0);
            } else {
                #pragma unroll
                for (int cg = 0; cg < 4; ++cg)
                    #pragma unroll
                    for (int rg = 0; rg < 4; ++rg)
                        acc[rg][cg] = __builtin_amdgcn_mfma_f32_16x16x32_bf16(
                            a[rg][kt], bf[cg], acc[rg][cg], 0, 0, 0);
            }
            __builtin_amdgcn_s_setprio(0);
            __builtin_amdgcn_s_barrier();
        }

        // fold: per-ct min/max of M into running trackers
        #pragma unroll
        for (int rg = 0; rg < 4; ++rg)
            #pragma unroll
            for (int cg = 0; cg < 4; ++cg)
                #pragma unroll
                for (int r = 0; r < 4; ++r) {
                    float m = acc[rg][cg][r];
                    mn4[rg][r] = fminf(mn4[rg][r], m);
                    mx4[rg][r] = fmaxf(mx4[rg][r], m);
                }
        ybase += 16384;  // loop-carried: blocks cross-ct hoisting
    }

    // Single epilogue: quad-lane reduce, eval C twice (quasiconcavity),
    // fire-and-forget atomicMin (no read guard -- R3 post-mortem).
    #pragma unroll
    for (int rg = 0; rg < 4; ++rg) {
        #pragma unroll
        for (int r = 0; r < 4; ++r) {
            float mn = mn4[rg][r];
            float mx = mx4[rg][r];
            #pragma unroll
            for (int mofs = 1; mofs < 16; mofs <<= 1) {
                mn = fminf(mn, __shfl_xor(mn, mofs, 64));
                mx = fmaxf(mx, __shfl_xor(mx, mofs, 64));
            }
            if (lm == 0) {
                float cmin = fminf(c_of_m(mn), c_of_m(mx));
                int row = rowStart + w * 64 + rg * 16 + lq * 4 + r;
                atomicMinFloat(&out[row], cmin);
            }
        }
    }
}

extern "C" void kernel_launch(void* const* d_in, const int* in_sizes, int n_in,
                              void* d_out, int out_size, void* d_ws, size_t ws_size,
                              hipStream_t stream) {
    const float* Ex = (const float*)d_in[0];
    const float* Ey = (const float*)d_in[1];
    float* out = (float*)d_out;
    u16* Xs = (u16*)d_ws;                // 4 MB, panel layout
    u16* Ys = Xs + (size_t)NROWS * DIM;  // 4 MB, panel layout

    hipLaunchKernelGGL(normalize_kernel, dim3(NROWS / 4, 2), dim3(256), 0, stream,
                       Ex, Ey, Xs, Ys, out);
    hipLaunchKernelGGL(gemm_min_kernel, dim3(16 * 16), dim3(512), 0, stream,
                       Xs, Ys, out);
}

// Round 5
// 94.820 us; speedup vs baseline: 1.0715x; 1.0190x over previous
//
#include <hip/hip_runtime.h>
#include <hip/hip_bf16.h>

typedef unsigned short u16;
typedef __attribute__((ext_vector_type(8))) short short8;
typedef __attribute__((ext_vector_type(4))) float floatx4;

#define NROWS 8192
#define DIM 256

__device__ __forceinline__ void atomicMinFloat(float* addr, float val) {
    if (val >= 0.0f) {
        atomicMin((int*)addr, __float_as_int(val));
    } else {
        atomicMax((unsigned int*)addr, __float_as_uint(val));
    }
}

__device__ __forceinline__ u16 f32_to_bf16_rne(float x) {
    unsigned int u = __float_as_uint(x);
    unsigned int r = (u + 0x7fffu + ((u >> 16) & 1u)) >> 16;
    return (u16)r;
}

// C(M) = -logp * exp(logp); quasiconcave in M => rowmin = min(C(minM), C(maxM)).
__device__ __forceinline__ float c_of_m(float m) {
    const float INV_SIG = 1.0f / 0.3f;
    const float KC = 0.28503427f;  // -ln(0.3) - 0.5*ln(2*pi)
    float z = (m - 1.0f) * INV_SIG;
    float logp = fmaf(-0.5f * z, z, KC);
    return -logp * __expf(logp);
}

// 16B async DMA global -> LDS. LDS dest is wave-uniform base + lane*16.
__device__ __forceinline__ void load16(const u16* g, u16* l) {
    __builtin_amdgcn_global_load_lds(
        (__attribute__((address_space(1))) void*)g,
        (__attribute__((address_space(3))) void*)l, 16, 0, 0);
}

// Normalize rows (L2-norm clamped at 1e-8), wave per row, float4 loads.
// BOTH X and Y are written in MFMA fragment ("panel") layout:
//   element (row r, k) -> flat[ ((p*8+kt)*64 + lq*16 + lm)*8 + j ]
//   p=r>>4, lm=r&15, kt=k>>5, lq=(k>>3)&3, j=k&7.
// A fragment load is then base + lane*16B: one coalesced dwordx4.
// Verified end-to-end R5/R11/R14/R15 (absmax 1.5e-5). [R20 int8 reverted]
__global__ __launch_bounds__(256) void normalize_kernel(const float* __restrict__ Ex,
                                                        const float* __restrict__ Ey,
                                                        u16* __restrict__ Xs,
                                                        u16* __restrict__ Ys,
                                                        float* __restrict__ out) {
    const int t = threadIdx.x;
    const int ln = t & 63;
    const int row = blockIdx.x * 4 + (t >> 6);
    const float* src = (blockIdx.y == 0) ? Ex : Ey;
    u16* dst = (blockIdx.y == 0) ? Xs : Ys;

    float4 v = *(const float4*)(src + (size_t)row * DIM + ln * 4);
    float s = fmaf(v.x, v.x, fmaf(v.y, v.y, fmaf(v.z, v.z, v.w * v.w)));
    #pragma unroll
    for (int m = 32; m >= 1; m >>= 1) s += __shfl_xor(s, m, 64);
    float inv = 1.0f / fmaxf(sqrtf(s), 1e-8f);

    ushort4 o;
    o.x = f32_to_bf16_rne(v.x * inv);
    o.y = f32_to_bf16_rne(v.y * inv);
    o.z = f32_to_bf16_rne(v.z * inv);
    o.w = f32_to_bf16_rne(v.w * inv);

    const int p = row >> 4;
    const int lm = row & 15;
    const int kt = ln >> 3;
    const int lq = (ln >> 1) & 3;
    const int j4 = (ln & 1) * 4;
    const size_t off = ((size_t)((p * 8 + kt) * 64 + lq * 16 + lm)) * 8 + j4;
    *(ushort4*)(dst + off) = o;

    if (blockIdx.y == 0 && ln == 0) out[row] = __uint_as_float(0x7f800000u);  // +inf
}

// R21: occupancy attack. bf16 datapath restored (R20's int8 missed the
// 7.7e-5 tolerance). ONE 1024-thread block per CU (16 waves = 4 waves/SIMD,
// vs 8/2 before): wave w owns 32 rows (a[2][8] = 64 VGPR; fixed state
// ~112 VGPR, capped at 128 by launch_bounds -> the 16-waves/CU tier, m69).
// Rationale: setprio (R1) and 8-phase barriers (R3) were null/negative at
// 2 waves/SIMD -- the per-ct LDS phase (2k cyc), fold (0.5k) and drains
// serialized against MFMA (5k cyc/ct). At 4 waves/SIMD wave-level TLP
// cross-covers them (m114). Cost: B ds_read traffic doubles (512 KB/ct =
// 4096 cyc wall, still < MFMA 4966; conflict-free pattern unchanged).
// Everything else = the proven R0 structure: per-ct __syncthreads, batch
// DMA stage, compiler-pipelined kt loop, zero-C acc init.
// Grid 256 (1 block/CU); XCD swizzle keeps A+B in the local L2.
__global__ void __launch_bounds__(1024, 4)
gemm_min_kernel(const u16* __restrict__ Xs,
                const u16* __restrict__ Ys,
                float* __restrict__ out) {
    __shared__ u16 Bs[2][32 * 512];  // 2 x 32 KB

    const int tid = threadIdx.x;
    const int w = tid >> 6;      // 0..15 row-group (32 rows each)
    const int lane = tid & 63;
    const int lq = lane >> 4;
    const int lm = lane & 15;

    // XCD-aware remap (dispatch i -> XCD i&7 round-robin): XCD x gets a
    // 4 row-tile x 8 col-group region. Bijective over the 16x16 grid.
    const int i = blockIdx.x;
    const int x = i & 7;
    const int jj = i >> 3;                      // 0..31 within XCD
    const int rt = (x & 3) * 4 + (jj & 3);      // row-tile 0..15
    const int cgrp = (x >> 2) * 8 + (jj >> 2);  // col-group 0..15

    const int rowStart = rt * 512;
    const int rowPan0 = rt * 32 + w * 2;  // wave's 2 consecutive 16-row panels
    const u16* ybase = Ys + (size_t)cgrp * 32 * 4096;  // advances 16384/ct

    // Stage one 64col x 256k B tile (32 KB = 32 x 1 KB units) via DMA.
    // 16 waves x 2 units; unit u -> (panel u>>3, kt u&7); LDS slot u*512 so
    // fragment reads are Bs[(cg*8+kt)*512 + lane*8] (b128, conflict-free).
    auto stage1 = [&](int buf, const u16* yb, int iu) {
        const int u = w * 2 + iu;
        load16(yb + (u >> 3) * 4096 + (u & 7) * 512 + lane * 8,
               &Bs[buf][u * 512]);
    };

    short8 a[2][8];
    auto loadA = [&](int kt) {
        #pragma unroll
        for (int rg = 0; rg < 2; ++rg)
            a[rg][kt] = *(const short8*)(
                Xs + ((size_t)(rowPan0 + rg) * 8 + kt) * 512 + lane * 8);
    };

    floatx4 mn4[2], mx4[2];
    #pragma unroll
    for (int rg = 0; rg < 2; ++rg) {
        mn4[rg] = (floatx4){3.4e38f, 3.4e38f, 3.4e38f, 3.4e38f};
        mx4[rg] = (floatx4){-3.4e38f, -3.4e38f, -3.4e38f, -3.4e38f};
    }

    floatx4 acc[2][4];
    const floatx4 FZ = (floatx4){0.0f, 0.0f, 0.0f, 0.0f};

    auto compute = [&](int buf) {
        #pragma unroll
        for (int kt = 0; kt < 8; ++kt) {
            short8 bf[4];
            #pragma unroll
            for (int cg = 0; cg < 4; ++cg)
                bf[cg] = *(const short8*)(&Bs[buf][(cg * 8 + kt) * 512 + lane * 8]);
            if (kt == 0) {
                #pragma unroll
                for (int cg = 0; cg < 4; ++cg)
                    #pragma unroll
                    for (int rg = 0; rg < 2; ++rg)
                        acc[rg][cg] = __builtin_amdgcn_mfma_f32_16x16x32_bf16(
                            a[rg][0], bf[cg], FZ, 0, 0, 0);
            } else {
                #pragma unroll
                for (int cg = 0; cg < 4; ++cg)
                    #pragma unroll
                    for (int rg = 0; rg < 2; ++rg)
                        acc[rg][cg] = __builtin_amdgcn_mfma_f32_16x16x32_bf16(
                            a[rg][kt], bf[cg], acc[rg][cg], 0, 0, 0);
            }
        }
    };
    auto fold = [&]() {
        #pragma unroll
        for (int rg = 0; rg < 2; ++rg)
            #pragma unroll
            for (int cg = 0; cg < 4; ++cg)
                #pragma unroll
                for (int r = 0; r < 4; ++r) {
                    float m = acc[rg][cg][r];
                    mn4[rg][r] = fminf(mn4[rg][r], m);
                    mx4[rg][r] = fmaxf(mx4[rg][r], m);
                }
    };

    // --- ct = 0, peeled: overlap A prologue with B0 DMA ---
    stage1(0, ybase, 0); stage1(0, ybase, 1);
    loadA(0); loadA(1);
    __syncthreads();         // drains B0 DMA (+ the early A loads)
    stage1(1, ybase + 16384, 0); stage1(1, ybase + 16384, 1);  // prefetch ct=1
    loadA(2); loadA(3); loadA(4); loadA(5); loadA(6); loadA(7);
    compute(0);
    fold();
    ybase += 16384;

    // --- cts 1..7: steady state ---
    #pragma unroll 1
    for (int ct = 1; ct < 8; ++ct) {
        const int buf = ct & 1;
        __syncthreads();           // drains ct's B DMA (issued a full ct ago)
        if (ct < 7)
            stage1(buf ^ 1, ybase + 16384, 0), stage1(buf ^ 1, ybase + 16384, 1);
        compute(buf);
        fold();
        ybase += 16384;  // loop-carried: blocks cross-ct hoisting
    }

    // Single epilogue: quad-lane reduce, eval C twice (quasiconcavity),
    // fire-and-forget atomicMin (no read guard -- R3 post-mortem).
    #pragma unroll
    for (int rg = 0; rg < 2; ++rg) {
        #pragma unroll
        for (int r = 0; r < 4; ++r) {
            float mn = mn4[rg][r];
            float mx = mx4[rg][r];
            #pragma unroll
            for (int mofs = 1; mofs < 16; mofs <<= 1) {
                mn = fminf(mn, __shfl_xor(mn, mofs, 64));
                mx = fmaxf(mx, __shfl_xor(mx, mofs, 64));
            }
            if (lm == 0) {
                float cmin = fminf(c_of_m(mn), c_of_m(mx));
                int row = rowStart + w * 32 + rg * 16 + lq * 4 + r;
                atomicMinFloat(&out[row], cmin);
            }
        }
    }
}

extern "C" void kernel_launch(void* const* d_in, const int* in_sizes, int n_in,
                              void* d_out, int out_size, void* d_ws, size_t ws_size,
                              hipStream_t stream) {
    const float* Ex = (const float*)d_in[0];
    const float* Ey = (const float*)d_in[1];
    float* out = (float*)d_out;
    u16* Xs = (u16*)d_ws;                // 4 MB, panel layout
    u16* Ys = Xs + (size_t)NROWS * DIM;  // 4 MB, panel layout

    hipLaunchKernelGGL(normalize_kernel, dim3(NROWS / 4, 2), dim3(256), 0, stream,
                       Ex, Ey, Xs, Ys, out);
    hipLaunchKernelGGL(gemm_min_kernel, dim3(16 * 16), dim3(1024), 0, stream,
                       Xs, Ys, out);
}

// Round 6
// 94.521 us; speedup vs baseline: 1.0749x; 1.0032x over previous
//
#include <hip/hip_runtime.h>
#include <hip/hip_bf16.h>

typedef unsigned short u16;
typedef __attribute__((ext_vector_type(8))) short short8;
typedef __attribute__((ext_vector_type(4))) float floatx4;

#define NROWS 8192
#define DIM 256

__device__ __forceinline__ void atomicMinFloat(float* addr, float val) {
    if (val >= 0.0f) {
        atomicMin((int*)addr, __float_as_int(val));
    } else {
        atomicMax((unsigned int*)addr, __float_as_uint(val));
    }
}

__device__ __forceinline__ u16 f32_to_bf16_rne(float x) {
    unsigned int u = __float_as_uint(x);
    unsigned int r = (u + 0x7fffu + ((u >> 16) & 1u)) >> 16;
    return (u16)r;
}

// C(M) = -logp * exp(logp); quasiconcave in M => rowmin = min(C(minM), C(maxM)).
__device__ __forceinline__ float c_of_m(float m) {
    const float INV_SIG = 1.0f / 0.3f;
    const float KC = 0.28503427f;  // -ln(0.3) - 0.5*ln(2*pi)
    float z = (m - 1.0f) * INV_SIG;
    float logp = fmaf(-0.5f * z, z, KC);
    return -logp * __expf(logp);
}

// 16B async DMA global -> LDS. LDS dest is wave-uniform base + lane*16.
__device__ __forceinline__ void load16(const u16* g, u16* l) {
    __builtin_amdgcn_global_load_lds(
        (__attribute__((address_space(1))) void*)g,
        (__attribute__((address_space(3))) void*)l, 16, 0, 0);
}

// Normalize rows (L2-norm clamped at 1e-8), wave per row, float4 loads.
// BOTH X and Y are written in MFMA fragment ("panel") layout:
//   element (row r, k) -> flat[ ((p*8+kt)*64 + lq*16 + lm)*8 + j ]
//   p=r>>4, lm=r&15, kt=k>>5, lq=(k>>3)&3, j=k&7.
// A fragment load is then base + lane*16B: one coalesced dwordx4.
// Verified end-to-end R5/R11/R14/R15 (absmax 1.5e-5).
__global__ __launch_bounds__(256) void normalize_kernel(const float* __restrict__ Ex,
                                                        const float* __restrict__ Ey,
                                                        u16* __restrict__ Xs,
                                                        u16* __restrict__ Ys,
                                                        float* __restrict__ out) {
    const int t = threadIdx.x;
    const int ln = t & 63;
    const int row = blockIdx.x * 4 + (t >> 6);
    const float* src = (blockIdx.y == 0) ? Ex : Ey;
    u16* dst = (blockIdx.y == 0) ? Xs : Ys;

    float4 v = *(const float4*)(src + (size_t)row * DIM + ln * 4);
    float s = fmaf(v.x, v.x, fmaf(v.y, v.y, fmaf(v.z, v.z, v.w * v.w)));
    #pragma unroll
    for (int m = 32; m >= 1; m >>= 1) s += __shfl_xor(s, m, 64);
    float inv = 1.0f / fmaxf(sqrtf(s), 1e-8f);

    ushort4 o;
    o.x = f32_to_bf16_rne(v.x * inv);
    o.y = f32_to_bf16_rne(v.y * inv);
    o.z = f32_to_bf16_rne(v.z * inv);
    o.w = f32_to_bf16_rne(v.w * inv);

    const int p = row >> 4;
    const int lm = row & 15;
    const int kt = ln >> 3;
    const int lq = (ln >> 1) & 3;
    const int j4 = (ln & 1) * 4;
    const size_t off = ((size_t)((p * 8 + kt) * 64 + lq * 16 + lm)) * 8 + j4;
    *(ushort4*)(dst + off) = o;

    if (blockIdx.y == 0 && ln == 0) out[row] = __uint_as_float(0x7f800000u);  // +inf
}

// R22: register-headroom attack. R0 (8 waves, ~250 VGPR) had ~6 free VGPR:
// the compiler could NOT hoist next-kt B-reads (16 VGPR) under MFMAs ->
// per-kt LDS latency exposure. R5 (16 waves) had headroom but doubled LDS
// traffic past the MFMA time -> LDS-BW-bound. Fix: 8 waves (LDS/ct = 62% of
// MFMA) with a 32-COL ct (16 cts of 32 cols): acc[4][2]=32 VGPR (was 64),
// mandatory state = a128+acc32+mnmx32 = 192, ~30 free -> the fully-unrolled
// kt loop lets the scheduler pipeline the 2-fragment (8 VGPR) B-reads 2-3
// kt-steps (~300 cyc) ahead. DMA/panel layout/epilogue math unchanged
// (cg range 4->2, B stride 16384->8192 u16). No setprio (R1 null), no extra
// barriers (R3 negative). Grid 256 (1 block/CU); XCD swizzle keeps A+B in
// the local L2 (A 1 MB + B 2 MB < 4 MB).
__global__ void __launch_bounds__(512, 2)
gemm_min_kernel(const u16* __restrict__ Xs,
                const u16* __restrict__ Ys,
                float* __restrict__ out) {
    __shared__ u16 Bs[2][16 * 512];  // 2 x 16 KB

    const int tid = threadIdx.x;
    const int w = tid >> 6;      // 0..7 row-group (64 rows each)
    const int lane = tid & 63;
    const int lq = lane >> 4;
    const int lm = lane & 15;

    // XCD-aware remap (dispatch i -> XCD i&7 round-robin): XCD x gets a
    // 4 row-tile x 8 col-group region. Bijective over the 16x16 grid.
    const int i = blockIdx.x;
    const int x = i & 7;
    const int jj = i >> 3;                      // 0..31 within XCD
    const int rt = (x & 3) * 4 + (jj & 3);      // row-tile 0..15
    const int cgrp = (x >> 2) * 8 + (jj >> 2);  // col-group 0..15

    const int rowStart = rt * 512;
    const int rowPan0 = rt * 32 + w * 4;
    const u16* ybase = Ys + (size_t)cgrp * 32 * 4096;  // advances 8192 u16/ct

    // Stage one 32col x 256k B tile (16 KB = 16 x 1 KB units) via DMA.
    // 8 waves x 2 units; unit u -> (col-panel u>>3, kt u&7); LDS slot u*512
    // so fragment reads are Bs[(cg*8+kt)*512 + lane*8] (b128, conflict-free).
    auto stage1 = [&](int buf, const u16* yb, int iu) {
        const int u = w * 2 + iu;
        load16(yb + (u >> 3) * 4096 + (u & 7) * 512 + lane * 8,
               &Bs[buf][u * 512]);
    };

    short8 a[4][8];
    auto loadA = [&](int kt) {
        #pragma unroll
        for (int rg = 0; rg < 4; ++rg)
            a[rg][kt] = *(const short8*)(
                Xs + ((size_t)(rowPan0 + rg) * 8 + kt) * 512 + lane * 8);
    };

    floatx4 mn4[4], mx4[4];
    #pragma unroll
    for (int rg = 0; rg < 4; ++rg) {
        mn4[rg] = (floatx4){3.4e38f, 3.4e38f, 3.4e38f, 3.4e38f};
        mx4[rg] = (floatx4){-3.4e38f, -3.4e38f, -3.4e38f, -3.4e38f};
    }

    floatx4 acc[4][2];
    const floatx4 FZ = (floatx4){0.0f, 0.0f, 0.0f, 0.0f};

    auto compute = [&](int buf) {
        #pragma unroll
        for (int kt = 0; kt < 8; ++kt) {
            short8 bf[2];
            #pragma unroll
            for (int cg = 0; cg < 2; ++cg)
                bf[cg] = *(const short8*)(&Bs[buf][(cg * 8 + kt) * 512 + lane * 8]);
            if (kt == 0) {
                #pragma unroll
                for (int cg = 0; cg < 2; ++cg)
                    #pragma unroll
                    for (int rg = 0; rg < 4; ++rg)
                        acc[rg][cg] = __builtin_amdgcn_mfma_f32_16x16x32_bf16(
                            a[rg][0], bf[cg], FZ, 0, 0, 0);
            } else {
                #pragma unroll
                for (int cg = 0; cg < 2; ++cg)
                    #pragma unroll
                    for (int rg = 0; rg < 4; ++rg)
                        acc[rg][cg] = __builtin_amdgcn_mfma_f32_16x16x32_bf16(
                            a[rg][kt], bf[cg], acc[rg][cg], 0, 0, 0);
            }
        }
    };
    auto fold = [&]() {
        #pragma unroll
        for (int rg = 0; rg < 4; ++rg)
            #pragma unroll
            for (int cg = 0; cg < 2; ++cg)
                #pragma unroll
                for (int r = 0; r < 4; ++r) {
                    float m = acc[rg][cg][r];
                    mn4[rg][r] = fminf(mn4[rg][r], m);
                    mx4[rg][r] = fmaxf(mx4[rg][r], m);
                }
    };

    // --- ct = 0, peeled: overlap A prologue with B0 DMA ---
    stage1(0, ybase, 0); stage1(0, ybase, 1);
    loadA(0); loadA(1);
    __syncthreads();         // drains B0 DMA (+ the early A loads)
    stage1(1, ybase + 8192, 0); stage1(1, ybase + 8192, 1);  // prefetch ct=1
    loadA(2); loadA(3); loadA(4); loadA(5); loadA(6); loadA(7);
    compute(0);
    fold();
    ybase += 8192;

    // --- cts 1..15: steady state ---
    #pragma unroll 1
    for (int ct = 1; ct < 16; ++ct) {
        const int buf = ct & 1;
        __syncthreads();           // drains ct's B DMA (issued a full ct ago)
        if (ct < 15)
            stage1(buf ^ 1, ybase + 8192, 0), stage1(buf ^ 1, ybase + 8192, 1);
        compute(buf);
        fold();
        ybase += 8192;  // loop-carried: blocks cross-ct hoisting
    }

    // Single epilogue: quad-lane reduce, eval C twice (quasiconcavity),
    // fire-and-forget atomicMin (no read guard -- R3 post-mortem).
    #pragma unroll
    for (int rg = 0; rg < 4; ++rg) {
        #pragma unroll
        for (int r = 0; r < 4; ++r) {
            float mn = mn4[rg][r];
            float mx = mx4[rg][r];
            #pragma unroll
            for (int mofs = 1; mofs < 16; mofs <<= 1) {
                mn = fminf(mn, __shfl_xor(mn, mofs, 64));
                mx = fmaxf(mx, __shfl_xor(mx, mofs, 64));
            }
            if (lm == 0) {
                float cmin = fminf(c_of_m(mn), c_of_m(mx));
                int row = rowStart + w * 64 + rg * 16 + lq * 4 + r;
                atomicMinFloat(&out[row], cmin);
            }
        }
    }
}

extern "C" void kernel_launch(void* const* d_in, const int* in_sizes, int n_in,
                              void* d_out, int out_size, void* d_ws, size_t ws_size,
                              hipStream_t stream) {
    const float* Ex = (const float*)d_in[0];
    const float* Ey = (const float*)d_in[1];
    float* out = (float*)d_out;
    u16* Xs = (u16*)d_ws;                // 4 MB, panel layout
    u16* Ys = Xs + (size_t)NROWS * DIM;  // 4 MB, panel layout

    hipLaunchKernelGGL(normalize_kernel, dim3(NROWS / 4, 2), dim3(256), 0, stream,
                       Ex, Ey, Xs, Ys, out);
    hipLaunchKernelGGL(gemm_min_kernel, dim3(16 * 16), dim3(512), 0, stream,
                       Xs, Ys, out);
}